// Round 6
// baseline (2352.636 us; speedup 1.0000x reference)
//
#include <hip/hip_runtime.h>
#include <hip/hip_bf16.h>

typedef __bf16 bf16_t;
typedef __bf16 bf16x8 __attribute__((ext_vector_type(8)));
typedef float f32x4 __attribute__((ext_vector_type(4)));

#define GLOAD16(gp, lp) __builtin_amdgcn_global_load_lds(                      \
    (const __attribute__((address_space(1))) void*)(gp),                       \
    (__attribute__((address_space(3))) void*)(lp), 16, 0, 0)
#define BARRIER() asm volatile("s_barrier" ::: "memory")
#define VMC(n) asm volatile("s_waitcnt vmcnt(" #n ")" ::: "memory")
#define LGK(n)                                                                 \
  do {                                                                         \
    asm volatile("s_waitcnt lgkmcnt(" #n ")" ::: "memory");                    \
    __builtin_amdgcn_sched_barrier(0);                                         \
  } while (0)

// ---------------- cast fp32 -> bf16 (vectorized x8) ----------------
__global__ __launch_bounds__(256) void cast_f32_bf16_k(
    const float* __restrict__ in, bf16_t* __restrict__ out, long n8) {
  long i = (long)blockIdx.x * blockDim.x + threadIdx.x;
  long stride = (long)gridDim.x * blockDim.x;
  for (; i < n8; i += stride) {
    long e = i * 8;
    float4 a = *(const float4*)(in + e);
    float4 b = *(const float4*)(in + e + 4);
    bf16x8 o;
    o[0] = (__bf16)a.x; o[1] = (__bf16)a.y; o[2] = (__bf16)a.z; o[3] = (__bf16)a.w;
    o[4] = (__bf16)b.x; o[5] = (__bf16)b.y; o[6] = (__bf16)b.z; o[7] = (__bf16)b.w;
    *(bf16x8*)(out + e) = o;
  }
}

// ============ 256x256-tile 8-wave GEMM, BK=64, 4-phase/K-tile schedule =====
// LDS: 2 buffers x 64KB {A: 256 rows x 128B, B: 256 rows x 128B}.
// Swizzle: 16B slot ^= (row&7); staging inverse-swizzles the global source.
// Phase P reads the subtile for phase P+2 (lgkmcnt(12)); stages one half-tile
// 4 phases ahead of its first read (vmcnt(6) pre-barrier). 16 MFMA per phase.

// reads: A-subtile ih (8 x b128) / B-subtile jh (4 x b128)
#define RDA(arr, base, ih)                                                     \
  {                                                                            \
    _Pragma("unroll") for (int ri = 0; ri < 4; ++ri) {                         \
      arr[ri * 2] =                                                            \
          *(const bf16x8*)(lds + (base) + aoffb + (ih)*8192 + ri * 2048 + sl0);\
      arr[ri * 2 + 1] =                                                        \
          *(const bf16x8*)(lds + (base) + aoffb + (ih)*8192 + ri * 2048 + sl1);\
    }                                                                          \
  }
#define RDB(arr, base, jh)                                                     \
  {                                                                            \
    _Pragma("unroll") for (int rj = 0; rj < 2; ++rj) {                         \
      arr[rj * 2] =                                                            \
          *(const bf16x8*)(lds + (base) + boffb + (jh)*4096 + rj * 2048 + sl0);\
      arr[rj * 2 + 1] =                                                        \
          *(const bf16x8*)(lds + (base) + boffb + (jh)*4096 + rj * 2048 + sl1);\
    }                                                                          \
  }
// stage half-tile h of K-tile U (2 x global_load_lds per thread)
#define STG_A(h, U)                                                            \
  {                                                                            \
    const bf16_t* s_ = Ap + (long)(h)*128 * Kl + (long)(U)*64;                 \
    char* d_ = lds + (((U)&1) * 65536) + (h)*16384 + dstA;                     \
    GLOAD16(s_, d_);                                                           \
    GLOAD16(s_ + 64 * Kl, d_ + 8192);                                          \
  }
#define STG_B(h, U)                                                            \
  {                                                                            \
    const bf16_t* s_ = Bp + (long)(h)*128 * Kl + (long)(U)*64;                 \
    char* d_ = lds + (((U)&1) * 65536) + 32768 + (h)*16384 + dstA;             \
    GLOAD16(s_, d_);                                                           \
    GLOAD16(s_ + 64 * Kl, d_ + 8192);                                          \
  }
// one C-quadrant: 4i x 2j x 2kk = 16 MFMA
#define QUAD(AV, BV, I0, J0)                                                   \
  {                                                                            \
    __builtin_amdgcn_s_setprio(1);                                             \
    _Pragma("unroll") for (int i = 0; i < 4; ++i)                              \
        _Pragma("unroll") for (int j = 0; j < 2; ++j)                          \
            _Pragma("unroll") for (int kk = 0; kk < 2; ++kk)                   \
                acc[I0 + i][J0 + j] = __builtin_amdgcn_mfma_f32_16x16x32_bf16( \
                    AV[i * 2 + kk], BV[j * 2 + kk], acc[I0 + i][J0 + j], 0, 0, \
                    0);                                                        \
    __builtin_amdgcn_s_setprio(0);                                             \
  }

template <int BIAS, bool MUL>
__global__ __launch_bounds__(512, 2) void gemm256(
    const bf16_t* __restrict__ A, const bf16_t* __restrict__ B,
    const float* __restrict__ bias, const bf16_t* __restrict__ mulm,
    bf16_t* __restrict__ out, int M, int N, int K) {
  __shared__ __align__(1024) char lds[131072];
  const int tid = threadIdx.x;
  const int gx = N >> 8;
  int bid = blockIdx.y * gx + blockIdx.x;
  const int nwg = gridDim.x * gridDim.y;  // multiple of 8 for our shapes
  const int cpx = nwg >> 3;
  bid = (bid & 7) * cpx + (bid >> 3);     // XCD-aware bijective swizzle
  const long row0 = (long)(bid / gx) * 256;
  const long col0 = (long)(bid % gx) * 256;
  const long Kl = K;

  const int w = tid >> 6, lane = tid & 63;
  const int wm = w >> 2, wn = w & 3;      // 2M x 4N waves
  const int fr = lane & 15, fq = lane >> 4;

  // read-side bases (slot ^= row&7; row&7 == fr&7 here)
  const int aoffb = wm * 16384 + fr * 128;
  const int boffb = 32768 + wn * 8192 + fr * 128;
  const int sl0 = ((fq ^ (fr & 7)) << 4);
  const int sl1 = (((4 | fq) ^ (fr & 7)) << 4);

  // staging: phys p = tid*16 (+8192); row=tid>>3, phys slot=tid&7;
  // source k-chunk = (tid&7) ^ (row&7)  (same for both loads)
  const int r0 = tid >> 3;
  const int s0 = (tid & 7) ^ (r0 & 7);
  const bf16_t* Ap = A + (row0 + r0) * Kl + s0 * 8;
  const bf16_t* Bp = B + (col0 + r0) * Kl + s0 * 8;
  const int dstA = w * 1024;

  f32x4 acc[8][4] = {};
  bf16x8 a0v[8], a1v[8], bv0a[4], bv0b[4], bv1[4];
  const int NT = K >> 6;  // even, >= 4

  // ---- prologue: stage t0 (4 halves) + t1 {B0,A0,B1}; vmcnt(6); reads t0
  STG_A(0, 0); STG_A(1, 0); STG_B(0, 0); STG_B(1, 0);
  STG_B(0, 1); STG_A(0, 1); STG_B(1, 1);
  VMC(6);
  BARRIER();
  RDB(bv0a, 0, 0);   // B0(0)
  RDA(a0v, 0, 0);    // A0(0)
  RDB(bv1, 0, 1);    // B1(0)

  // ---- steady tiles, pairs (par 0 then 1); covers T = 0 .. NT-3
#define TILE_STEADY(T, CB, NB, BVC, BVN)                                       \
  {                                                                            \
    /* ph0 */                                                                  \
    RDA(a1v, CB, 1);                                                           \
    STG_A(1, (T) + 1);                                                         \
    VMC(6); BARRIER(); LGK(12);                                                \
    QUAD(a0v, BVC, 0, 0);                                                      \
    BARRIER();                                                                 \
    /* ph1 */                                                                  \
    RDB(BVN, NB, 0);                                                           \
    STG_B(0, (T) + 2);                                                         \
    VMC(6); BARRIER(); LGK(12);                                                \
    QUAD(a0v, bv1, 0, 2);                                                      \
    BARRIER();                                                                 \
    /* ph2 */                                                                  \
    RDA(a0v, NB, 0);                                                           \
    STG_A(0, (T) + 2);                                                         \
    VMC(6); BARRIER(); LGK(12);                                                \
    QUAD(a1v, bv1, 4, 2);                                                      \
    BARRIER();                                                                 \
    /* ph3 */                                                                  \
    RDB(bv1, NB, 1);                                                           \
    STG_B(1, (T) + 2);                                                         \
    VMC(6); BARRIER(); LGK(12);                                                \
    QUAD(a1v, BVC, 4, 0);                                                      \
    BARRIER();                                                                 \
  }

  int T = 0;
  for (; T + 3 < NT; T += 2) {
    TILE_STEADY(T, 0, 65536, bv0a, bv0b);
    TILE_STEADY(T + 1, 65536, 0, bv0b, bv0a);
  }
  // ---- tail tile NT-2 (par 0): stage only A1(NT-1); vmcnt {6,4,2,0}
  {
    RDA(a1v, 0, 1);
    STG_A(1, NT - 1);
    VMC(6); BARRIER(); LGK(12);
    QUAD(a0v, bv0a, 0, 0);
    BARRIER();
    RDB(bv0b, 65536, 0);
    VMC(4); BARRIER(); LGK(12);
    QUAD(a0v, bv1, 0, 2);
    BARRIER();
    RDA(a0v, 65536, 0);
    VMC(2); BARRIER(); LGK(12);
    QUAD(a1v, bv1, 4, 2);
    BARRIER();
    RDB(bv1, 65536, 1);
    VMC(0); BARRIER(); LGK(12);
    QUAD(a1v, bv0a, 4, 0);
    BARRIER();
  }
  // ---- tail tile NT-1 (par 1): register-only finish
  {
    RDA(a1v, 65536, 1);
    LGK(12);
    QUAD(a0v, bv0b, 0, 0);
    LGK(8);
    QUAD(a0v, bv1, 0, 2);
    LGK(0);
    QUAD(a1v, bv1, 4, 2);
    QUAD(a1v, bv0b, 4, 0);
  }
#undef TILE_STEADY

  // epilogue: C/D layout col=lane&15, row=(lane>>4)*4+r
#pragma unroll
  for (int i = 0; i < 8; ++i)
#pragma unroll
    for (int j = 0; j < 4; ++j)
#pragma unroll
      for (int r = 0; r < 4; ++r) {
        long gi = row0 + wm * 128 + i * 16 + fq * 4 + r;
        long gj = col0 + wn * 64 + j * 16 + fr;
        float v = acc[i][j][r];
        if (BIAS == 1) v += bias[gj];
        long idx = gi * (long)N + gj;
        if (MUL) v *= (float)mulm[idx];
        out[idx] = (bf16_t)v;
      }
}

// ---------------- NT GEMM (m97 128x128), slot-swizzled, XCD-grouped --------
// GROUP 0: blocks sharing an A row-tile grouped on one XCD (requires gy%8==0)
// GROUP 1: blocks sharing a B col-tile grouped on one XCD (requires gx%8==0)
template <int BIAS, bool MUL, bool RES, bool OUTBF16, int GROUP>
__global__ __launch_bounds__(256) void gemm_nt(
    const bf16_t* __restrict__ A, const bf16_t* __restrict__ B,
    const float* __restrict__ bias, const bf16_t* __restrict__ mulm,
    const float* __restrict__ res, float* __restrict__ outf,
    bf16_t* __restrict__ outb, int M, int N, int K) {
  __shared__ bf16_t As[128 * 32];
  __shared__ bf16_t Bs[128 * 32];
  const int tid = threadIdx.x;
  const int gx = gridDim.x, gy = gridDim.y;
  const int n = blockIdx.y * gx + blockIdx.x;
  const int xcd = n & 7, q = n >> 3;
  int br, bc;
  if (GROUP == 0) { br = xcd + 8 * (q / gx); bc = q % gx; }
  else            { bc = xcd + 8 * (q / gy); br = q % gy; }
  const long row0 = (long)br * 128;
  const long col0 = (long)bc * 128;
  const int wid = tid >> 6, lane = tid & 63;
  const int wr = (wid >> 1) * 64;
  const int wc = (wid & 1) * 64;
  const int fr = lane & 15, fq = lane >> 4;
  const int sx = (fr >> 1) & 3;
  const int srow = tid >> 2;
  const int scol = ((tid & 3) ^ ((srow >> 1) & 3)) * 8;  // inverse-swz source

  f32x4 acc[4][4] = {};

  const bf16_t* Ag = A + (row0 + srow) * (long)K + scol;
  const bf16_t* Bg = B + (col0 + srow) * (long)K + scol;
  const long k64 = 64L * K;
  bf16_t* ldsA = As + wid * 512;
  bf16_t* ldsB = Bs + wid * 512;

  for (int k0 = 0; k0 < K; k0 += 32) {
    GLOAD16(Ag + k0, ldsA);
    GLOAD16(Ag + k0 + k64, ldsA + 2048);
    GLOAD16(Bg + k0, ldsB);
    GLOAD16(Bg + k0 + k64, ldsB + 2048);
    __syncthreads();
    bf16x8 av[4], bv[4];
#pragma unroll
    for (int i = 0; i < 4; i++)
      av[i] = *(const bf16x8*)(As + (wr + i * 16 + fr) * 32 + ((fq ^ sx) << 3));
#pragma unroll
    for (int j = 0; j < 4; j++)
      bv[j] = *(const bf16x8*)(Bs + (wc + j * 16 + fr) * 32 + ((fq ^ sx) << 3));
#pragma unroll
    for (int i = 0; i < 4; i++)
#pragma unroll
      for (int j = 0; j < 4; j++)
        acc[i][j] = __builtin_amdgcn_mfma_f32_16x16x32_bf16(av[i], bv[j],
                                                            acc[i][j], 0, 0, 0);
    __syncthreads();
  }

#pragma unroll
  for (int i = 0; i < 4; i++) {
#pragma unroll
    for (int j = 0; j < 4; j++) {
#pragma unroll
      for (int r = 0; r < 4; r++) {
        long gi = row0 + wr + i * 16 + fq * 4 + r;
        long gj = col0 + wc + j * 16 + fr;
        float v = acc[i][j][r];
        if (BIAS == 1) v += bias[gj];
        if (BIAS == 2) v += bias[gi];
        long idx = gi * (long)N + gj;
        if (MUL) v *= (float)mulm[idx];
        if (RES) v += res[idx];
        if (OUTBF16) outb[idx] = (bf16_t)v;
        else outf[idx] = v;
      }
    }
  }
}

// ---------------- row softmax over 8192 cols, bf16 in-place ----------------
__global__ __launch_bounds__(256) void softmax_bf16_inplace(
    bf16_t* __restrict__ buf) {
  const long row = blockIdx.x;
  bf16_t* p = buf + row * 8192;
  const int t = threadIdx.x;
  float v[32];
#pragma unroll
  for (int i = 0; i < 4; i++) {
    bf16x8 raw = *(const bf16x8*)(p + t * 32 + i * 8);
#pragma unroll
    for (int j = 0; j < 8; j++) v[i * 8 + j] = (float)raw[j];
  }
  float m = -1e30f;
#pragma unroll
  for (int i = 0; i < 32; i++) m = fmaxf(m, v[i]);
  for (int off = 32; off; off >>= 1) m = fmaxf(m, __shfl_xor(m, off, 64));
  __shared__ float redm[4], reds[4];
  if ((t & 63) == 0) redm[t >> 6] = m;
  __syncthreads();
  m = fmaxf(fmaxf(redm[0], redm[1]), fmaxf(redm[2], redm[3]));
  float s = 0.f;
#pragma unroll
  for (int i = 0; i < 32; i++) {
    v[i] = __expf(v[i] - m);
    s += v[i];
  }
  for (int off = 32; off; off >>= 1) s += __shfl_xor(s, off, 64);
  if ((t & 63) == 0) reds[t >> 6] = s;
  __syncthreads();
  s = reds[0] + reds[1] + reds[2] + reds[3];
  float inv = 1.0f / s;
#pragma unroll
  for (int i = 0; i < 4; i++) {
    bf16x8 o;
#pragma unroll
    for (int j = 0; j < 8; j++) o[j] = (bf16_t)(v[i * 8 + j] * inv);
    *(bf16x8*)(p + t * 32 + i * 8) = o;
  }
}

// --------- row softmax: bf16 logits in, fp32 out + bf16 in-place ----------
__global__ __launch_bounds__(256) void softmax_f_k(bf16_t* __restrict__ fm,
                                                   float* __restrict__ outf) {
  const long row = blockIdx.x;
  bf16_t* p = fm + row * 8192;
  float* q = outf + row * 8192;
  const int t = threadIdx.x;
  float v[32];
#pragma unroll
  for (int i = 0; i < 4; i++) {
    bf16x8 raw = *(const bf16x8*)(p + t * 32 + i * 8);
#pragma unroll
    for (int j = 0; j < 8; j++) v[i * 8 + j] = (float)raw[j];
  }
  float m = -1e30f;
#pragma unroll
  for (int i = 0; i < 32; i++) m = fmaxf(m, v[i]);
  for (int off = 32; off; off >>= 1) m = fmaxf(m, __shfl_xor(m, off, 64));
  __shared__ float redm[4], reds[4];
  if ((t & 63) == 0) redm[t >> 6] = m;
  __syncthreads();
  m = fmaxf(fmaxf(redm[0], redm[1]), fmaxf(redm[2], redm[3]));
  float s = 0.f;
#pragma unroll
  for (int i = 0; i < 32; i++) {
    v[i] = __expf(v[i] - m);
    s += v[i];
  }
  for (int off = 32; off; off >>= 1) s += __shfl_xor(s, off, 64);
  if ((t & 63) == 0) reds[t >> 6] = s;
  __syncthreads();
  s = reds[0] + reds[1] + reds[2] + reds[3];
  float inv = 1.0f / s;
#pragma unroll
  for (int i = 0; i < 8; i++) {
    float4 o;
    o.x = v[i * 4 + 0] * inv;
    o.y = v[i * 4 + 1] * inv;
    o.z = v[i * 4 + 2] * inv;
    o.w = v[i * 4 + 3] * inv;
    *(float4*)(q + t * 32 + i * 4) = o;
  }
#pragma unroll
  for (int i = 0; i < 4; i++) {
    bf16x8 o;
#pragma unroll
    for (int j = 0; j < 8; j++) o[j] = (bf16_t)(v[i * 8 + j] * inv);
    *(bf16x8*)(p + t * 32 + i * 8) = o;
  }
}

// ---------------------------------------------------------------------------
extern "C" void kernel_launch(void* const* d_in, const int* in_sizes, int n_in,
                              void* d_out, int out_size, void* d_ws,
                              size_t ws_size, hipStream_t stream) {
  const int N = 8192, C = 2048, IC = 1024;
  const float* x = (const float*)d_in[0];
  const float* theta_w = (const float*)d_in[1];
  const float* theta_b = (const float*)d_in[2];
  const float* phi_w = (const float*)d_in[3];
  const float* phi_b = (const float*)d_in[4];
  const float* g_w = (const float*)d_in[5];
  const float* g_b = (const float*)d_in[6];
  const float* W_w = (const float*)d_in[7];
  const float* W_b = (const float*)d_in[8];
  const float* mask_w = (const float*)d_in[9];
  const float* mask_b = (const float*)d_in[10];

  float* z_out = (float*)d_out;            // [N,C] fp32
  float* f_out = z_out + (long)N * C;      // [N,N] fp32

  // d_out-hosted scratch (dead before those regions' final writes):
  bf16_t* ML = (bf16_t*)f_out;             // [N,N] bf16 mask logits -> mask
  bf16_t* th16 = (bf16_t*)z_out;           // [N,IC]
  bf16_t* ph16 = th16 + (long)N * IC;      // [N,IC]
  bf16_t* gT16 = ph16 + (long)N * IC;      // [IC,N]

  char* w = (char*)d_ws;
  bf16_t* xb = (bf16_t*)w;      w += (long)N * C * 2;
  bf16_t* mwb = (bf16_t*)w;     w += (long)N * C * 2;
  bf16_t* thwb = (bf16_t*)w;    w += (long)IC * C * 2;
  bf16_t* phwb = (bf16_t*)w;    w += (long)IC * C * 2;
  bf16_t* gwb = (bf16_t*)w;     w += (long)IC * C * 2;
  bf16_t* Wwb = (bf16_t*)w;     w += (long)C * IC * 2;
  bf16_t* fm = (bf16_t*)w;      w += (long)N * N * 2;   // f*mask logits -> P
  bf16_t* y16 = (bf16_t*)w;     w += (long)N * IC * 2;

  cast_f32_bf16_k<<<8192, 256, 0, stream>>>(x, xb, (long)N * C / 8);
  cast_f32_bf16_k<<<8192, 256, 0, stream>>>(mask_w, mwb, (long)N * C / 8);
  cast_f32_bf16_k<<<1024, 256, 0, stream>>>(theta_w, thwb, (long)IC * C / 8);
  cast_f32_bf16_k<<<1024, 256, 0, stream>>>(phi_w, phwb, (long)IC * C / 8);
  cast_f32_bf16_k<<<1024, 256, 0, stream>>>(g_w, gwb, (long)IC * C / 8);
  cast_f32_bf16_k<<<1024, 256, 0, stream>>>(W_w, Wwb, (long)C * IC / 8);

  // projections (128^2 kernel, XCD-grouped)
  gemm_nt<1, false, false, true, 0><<<dim3(IC / 128, N / 128), 256, 0, stream>>>(
      xb, thwb, theta_b, nullptr, nullptr, nullptr, th16, N, IC, C);
  gemm_nt<1, false, false, true, 0><<<dim3(IC / 128, N / 128), 256, 0, stream>>>(
      xb, phwb, phi_b, nullptr, nullptr, nullptr, ph16, N, IC, C);
  gemm_nt<2, false, false, true, 1><<<dim3(N / 128, IC / 128), 256, 0, stream>>>(
      gwb, xb, g_b, nullptr, nullptr, nullptr, gT16, IC, N, C);
  // mask logits (256^2 4-phase kernel), bias per col
  gemm256<1, false><<<dim3(N / 256, N / 256), 512, 0, stream>>>(
      xb, mwb, mask_b, nullptr, ML, N, N, C);
  softmax_bf16_inplace<<<N, 256, 0, stream>>>(ML);
  // f*mask logits (256^2 4-phase kernel)
  gemm256<0, true><<<dim3(N / 256, N / 256), 512, 0, stream>>>(
      th16, ph16, nullptr, ML, fm, N, N, IC);
  softmax_f_k<<<N, 256, 0, stream>>>(fm, f_out);
  // y = P @ g_x (NT via gT16), XCD-grouped on A rows
  gemm_nt<0, false, false, true, 0><<<dim3(IC / 128, N / 128), 256, 0, stream>>>(
      fm, gT16, nullptr, nullptr, nullptr, nullptr, y16, N, IC, N);
  // z = y @ W_w^T + W_b + x
  gemm_nt<1, false, true, false, 0><<<dim3(C / 128, N / 128), 256, 0, stream>>>(
      y16, Wwb, W_b, nullptr, x, z_out, nullptr, N, C, IC);
}

// Round 7
// 1164.902 us; speedup vs baseline: 2.0196x; 2.0196x over previous
//
#include <hip/hip_runtime.h>
#include <hip/hip_bf16.h>

typedef __bf16 bf16_t;
typedef __bf16 bf16x8 __attribute__((ext_vector_type(8)));
typedef float f32x4 __attribute__((ext_vector_type(4)));

#define GLOAD16(gp, lp) __builtin_amdgcn_global_load_lds(                      \
    (const __attribute__((address_space(1))) void*)(gp),                       \
    (__attribute__((address_space(3))) void*)(lp), 16, 0, 0)
#define BARRIER() asm volatile("s_barrier" ::: "memory")
#define VMC(n) asm volatile("s_waitcnt vmcnt(" #n ")" ::: "memory")
#define LGK(n)                                                                 \
  do {                                                                         \
    asm volatile("s_waitcnt lgkmcnt(" #n ")" ::: "memory");                    \
    __builtin_amdgcn_sched_barrier(0);                                         \
  } while (0)

// ---------------- cast fp32 -> bf16 (vectorized x8) ----------------
__global__ __launch_bounds__(256) void cast_f32_bf16_k(
    const float* __restrict__ in, bf16_t* __restrict__ out, long n8) {
  long i = (long)blockIdx.x * blockDim.x + threadIdx.x;
  long stride = (long)gridDim.x * blockDim.x;
  for (; i < n8; i += stride) {
    long e = i * 8;
    float4 a = *(const float4*)(in + e);
    float4 b = *(const float4*)(in + e + 4);
    bf16x8 o;
    o[0] = (__bf16)a.x; o[1] = (__bf16)a.y; o[2] = (__bf16)a.z; o[3] = (__bf16)a.w;
    o[4] = (__bf16)b.x; o[5] = (__bf16)b.y; o[6] = (__bf16)b.z; o[7] = (__bf16)b.w;
    *(bf16x8*)(out + e) = o;
  }
}

// ============ 256x256-tile 8-wave GEMM, BK=32, 4-deep LDS pipeline =========
// Two phases per K-step (16 MFMA each) with distance-1 ds_read prefetch and
// counted lgkmcnt(4/8) + vmcnt(4); frag working set = 64 VGPR (no spill).
// LDS rows 64B; 16B slot XOR-swizzled by (row>>1)&3; staging inverse-swizzles
// the global source (linear LDS dest for global_load_lds).
template <int VM, bool ST, bool RDN>
__device__ __forceinline__ void kstepPh(
    int t, char* lds, const int (&aoff)[8], const int (&boff)[4],
    const bf16_t* As0, const bf16_t* As1, const bf16_t* Bs0,
    const bf16_t* Bs1, int dst0, int dst1, bf16x8 (&a0)[4], bf16x8 (&a1)[4],
    bf16x8 (&bvc)[4], bf16x8 (&bvn)[4], f32x4 (&acc)[8][4]) {
  char* cb = lds + (t & 3) * 32768;
  char* nb = lds + ((t + 1) & 3) * 32768;
  char* sb = lds + ((t + 3) & 3) * 32768;
  // ---- P0: read A1(t); stage A(t+3); wait prev-phase reads; MFMA rows 0..3
  if (VM == 4) VMC(4);
  else if (VM == 0) VMC(0);
  BARRIER();
#pragma unroll
  for (int i = 0; i < 4; ++i) a1[i] = *(const bf16x8*)(cb + aoff[4 + i]);
  if (ST) {
    GLOAD16(As0 + (long)(t + 3) * 32, sb + dst0);
    GLOAD16(As1 + (long)(t + 3) * 32, sb + dst1);
  }
  LGK(4);
  __builtin_amdgcn_s_setprio(1);
#pragma unroll
  for (int i = 0; i < 4; ++i)
#pragma unroll
    for (int j = 0; j < 4; ++j)
      acc[i][j] = __builtin_amdgcn_mfma_f32_16x16x32_bf16(a0[i], bvc[j],
                                                          acc[i][j], 0, 0, 0);
  __builtin_amdgcn_s_setprio(0);
  BARRIER();
  // ---- P1: read A0(t+1)+B(t+1); stage B(t+3); wait P0 reads; MFMA rows 4..7
  if (RDN) {
#pragma unroll
    for (int i = 0; i < 4; ++i) a0[i] = *(const bf16x8*)(nb + aoff[i]);
#pragma unroll
    for (int j = 0; j < 4; ++j)
      bvn[j] = *(const bf16x8*)(nb + 16384 + boff[j]);
  }
  if (ST) {
    GLOAD16(Bs0 + (long)(t + 3) * 32, sb + 16384 + dst0);
    GLOAD16(Bs1 + (long)(t + 3) * 32, sb + 16384 + dst1);
  }
  if (RDN) LGK(8);
  else LGK(0);
  __builtin_amdgcn_s_setprio(1);
#pragma unroll
  for (int i = 0; i < 4; ++i)
#pragma unroll
    for (int j = 0; j < 4; ++j)
      acc[4 + i][j] = __builtin_amdgcn_mfma_f32_16x16x32_bf16(a1[i], bvc[j],
                                                              acc[4 + i][j],
                                                              0, 0, 0);
  __builtin_amdgcn_s_setprio(0);
}

template <int BIAS, bool MUL>
__global__ __launch_bounds__(512, 2) void gemm256(
    const bf16_t* __restrict__ A, const bf16_t* __restrict__ B,
    const float* __restrict__ bias, const bf16_t* __restrict__ mulm,
    bf16_t* __restrict__ out, int M, int N, int K) {
  __shared__ __align__(1024) char lds[131072];
  const int tid = threadIdx.x;
  const int gx = N >> 8;
  int bid = blockIdx.y * gx + blockIdx.x;
  const int nwg = gridDim.x * gridDim.y;  // multiple of 8 for our shapes
  const int cpx = nwg >> 3;
  bid = (bid & 7) * cpx + (bid >> 3);     // XCD-aware bijective swizzle
  const long row0 = (long)(bid / gx) * 256;
  const long col0 = (long)(bid % gx) * 256;

  const int w = tid >> 6, lane = tid & 63;
  const int wm = w >> 2, wn = w & 3;      // 2M x 4N waves
  const int fr = lane & 15, fq = lane >> 4;
  const int sx = (fr >> 1) & 3;           // read-side swizzle (lane-const)

  int aoff[8], boff[4];
#pragma unroll
  for (int i = 0; i < 8; ++i)
    aoff[i] = (wm * 128 + i * 16 + fr) * 64 + ((fq ^ sx) << 4);
#pragma unroll
  for (int j = 0; j < 4; ++j)
    boff[j] = (wn * 64 + j * 16 + fr) * 64 + ((fq ^ sx) << 4);

  // staging: linear LDS dest; inverse-swizzled global k-chunk per phys slot
  const int p0 = w * 1024 + lane * 16;
  const int p1 = p0 + 8192;
  const int r0 = p0 >> 6, r1 = p1 >> 6;
  const int s0 = ((p0 >> 4) & 3) ^ ((r0 >> 1) & 3);
  const int s1 = ((p1 >> 4) & 3) ^ ((r1 >> 1) & 3);
  const bf16_t* As0 = A + (row0 + r0) * (long)K + (s0 << 3);
  const bf16_t* As1 = A + (row0 + r1) * (long)K + (s1 << 3);
  const bf16_t* Bs0 = B + (col0 + r0) * (long)K + (s0 << 3);
  const bf16_t* Bs1 = B + (col0 + r1) * (long)K + (s1 << 3);
  const int dst0 = w * 1024;
  const int dst1 = dst0 + 8192;

  f32x4 acc[8][4] = {};
  bf16x8 a0[4], a1[4], bv1[4], bv2[4];
  const int NT = K >> 5;  // even, >= 6

  // prologue: stage tiles 0,1,2; wait tile 0; read A0(0)+B(0) (8 reads)
#pragma unroll
  for (int t = 0; t < 3; ++t) {
    char* buf = lds + t * 32768;
    GLOAD16(As0 + (long)t * 32, buf + dst0);
    GLOAD16(As1 + (long)t * 32, buf + dst1);
    GLOAD16(Bs0 + (long)t * 32, buf + 16384 + dst0);
    GLOAD16(Bs1 + (long)t * 32, buf + 16384 + dst1);
  }
  VMC(8);
  BARRIER();
#pragma unroll
  for (int i = 0; i < 4; ++i) a0[i] = *(const bf16x8*)(lds + aoff[i]);
#pragma unroll
  for (int j = 0; j < 4; ++j) bv1[j] = *(const bf16x8*)(lds + 16384 + boff[j]);

  int t = 0;
  for (; t < NT - 4; t += 2) {
    kstepPh<4, true, true>(t, lds, aoff, boff, As0, As1, Bs0, Bs1, dst0, dst1,
                           a0, a1, bv1, bv2, acc);
    kstepPh<4, true, true>(t + 1, lds, aoff, boff, As0, As1, Bs0, Bs1, dst0,
                           dst1, a0, a1, bv2, bv1, acc);
  }
  kstepPh<4, true, true>(NT - 4, lds, aoff, boff, As0, As1, Bs0, Bs1, dst0,
                         dst1, a0, a1, bv1, bv2, acc);
  kstepPh<4, false, true>(NT - 3, lds, aoff, boff, As0, As1, Bs0, Bs1, dst0,
                          dst1, a0, a1, bv2, bv1, acc);
  kstepPh<0, false, true>(NT - 2, lds, aoff, boff, As0, As1, Bs0, Bs1, dst0,
                          dst1, a0, a1, bv1, bv2, acc);
  kstepPh<-1, false, false>(NT - 1, lds, aoff, boff, As0, As1, Bs0, Bs1, dst0,
                            dst1, a0, a1, bv2, bv1, acc);

  // epilogue: C/D layout col=lane&15, row=(lane>>4)*4+r
#pragma unroll
  for (int i = 0; i < 8; ++i)
#pragma unroll
    for (int j = 0; j < 4; ++j)
#pragma unroll
      for (int r = 0; r < 4; ++r) {
        long gi = row0 + wm * 128 + i * 16 + fq * 4 + r;
        long gj = col0 + wn * 64 + j * 16 + fr;
        float v = acc[i][j][r];
        if (BIAS == 1) v += bias[gj];
        long idx = gi * (long)N + gj;
        if (MUL) v *= (float)mulm[idx];
        out[idx] = (bf16_t)v;
      }
}

// ---------------- NT GEMM (m97 128x128), slot-swizzled, XCD-grouped --------
// GROUP 0: blocks sharing an A row-tile grouped on one XCD (requires gy%8==0)
// GROUP 1: blocks sharing a B col-tile grouped on one XCD (requires gx%8==0)
template <int BIAS, bool MUL, bool RES, bool OUTBF16, int GROUP>
__global__ __launch_bounds__(256) void gemm_nt(
    const bf16_t* __restrict__ A, const bf16_t* __restrict__ B,
    const float* __restrict__ bias, const bf16_t* __restrict__ mulm,
    const float* __restrict__ res, float* __restrict__ outf,
    bf16_t* __restrict__ outb, int M, int N, int K) {
  __shared__ bf16_t As[128 * 32];
  __shared__ bf16_t Bs[128 * 32];
  const int tid = threadIdx.x;
  const int gx = gridDim.x, gy = gridDim.y;
  const int n = blockIdx.y * gx + blockIdx.x;
  const int xcd = n & 7, q = n >> 3;
  int br, bc;
  if (GROUP == 0) { br = xcd + 8 * (q / gx); bc = q % gx; }
  else            { bc = xcd + 8 * (q / gy); br = q % gy; }
  const long row0 = (long)br * 128;
  const long col0 = (long)bc * 128;
  const int wid = tid >> 6, lane = tid & 63;
  const int wr = (wid >> 1) * 64;
  const int wc = (wid & 1) * 64;
  const int fr = lane & 15, fq = lane >> 4;
  const int sx = (fr >> 1) & 3;
  const int srow = tid >> 2;
  const int scol = ((tid & 3) ^ ((srow >> 1) & 3)) * 8;  // inverse-swz source

  f32x4 acc[4][4] = {};

  const bf16_t* Ag = A + (row0 + srow) * (long)K + scol;
  const bf16_t* Bg = B + (col0 + srow) * (long)K + scol;
  const long k64 = 64L * K;
  bf16_t* ldsA = As + wid * 512;
  bf16_t* ldsB = Bs + wid * 512;

  for (int k0 = 0; k0 < K; k0 += 32) {
    GLOAD16(Ag + k0, ldsA);
    GLOAD16(Ag + k0 + k64, ldsA + 2048);
    GLOAD16(Bg + k0, ldsB);
    GLOAD16(Bg + k0 + k64, ldsB + 2048);
    __syncthreads();
    bf16x8 av[4], bv[4];
#pragma unroll
    for (int i = 0; i < 4; i++)
      av[i] = *(const bf16x8*)(As + (wr + i * 16 + fr) * 32 + ((fq ^ sx) << 3));
#pragma unroll
    for (int j = 0; j < 4; j++)
      bv[j] = *(const bf16x8*)(Bs + (wc + j * 16 + fr) * 32 + ((fq ^ sx) << 3));
#pragma unroll
    for (int i = 0; i < 4; i++)
#pragma unroll
      for (int j = 0; j < 4; j++)
        acc[i][j] = __builtin_amdgcn_mfma_f32_16x16x32_bf16(av[i], bv[j],
                                                            acc[i][j], 0, 0, 0);
    __syncthreads();
  }

#pragma unroll
  for (int i = 0; i < 4; i++) {
#pragma unroll
    for (int j = 0; j < 4; j++) {
#pragma unroll
      for (int r = 0; r < 4; r++) {
        long gi = row0 + wr + i * 16 + fq * 4 + r;
        long gj = col0 + wc + j * 16 + fr;
        float v = acc[i][j][r];
        if (BIAS == 1) v += bias[gj];
        if (BIAS == 2) v += bias[gi];
        long idx = gi * (long)N + gj;
        if (MUL) v *= (float)mulm[idx];
        if (RES) v += res[idx];
        if (OUTBF16) outb[idx] = (bf16_t)v;
        else outf[idx] = v;
      }
    }
  }
}

// ---------------- row softmax over 8192 cols, bf16 in-place ----------------
__global__ __launch_bounds__(256) void softmax_bf16_inplace(
    bf16_t* __restrict__ buf) {
  const long row = blockIdx.x;
  bf16_t* p = buf + row * 8192;
  const int t = threadIdx.x;
  float v[32];
#pragma unroll
  for (int i = 0; i < 4; i++) {
    bf16x8 raw = *(const bf16x8*)(p + t * 32 + i * 8);
#pragma unroll
    for (int j = 0; j < 8; j++) v[i * 8 + j] = (float)raw[j];
  }
  float m = -1e30f;
#pragma unroll
  for (int i = 0; i < 32; i++) m = fmaxf(m, v[i]);
  for (int off = 32; off; off >>= 1) m = fmaxf(m, __shfl_xor(m, off, 64));
  __shared__ float redm[4], reds[4];
  if ((t & 63) == 0) redm[t >> 6] = m;
  __syncthreads();
  m = fmaxf(fmaxf(redm[0], redm[1]), fmaxf(redm[2], redm[3]));
  float s = 0.f;
#pragma unroll
  for (int i = 0; i < 32; i++) {
    v[i] = __expf(v[i] - m);
    s += v[i];
  }
  for (int off = 32; off; off >>= 1) s += __shfl_xor(s, off, 64);
  if ((t & 63) == 0) reds[t >> 6] = s;
  __syncthreads();
  s = reds[0] + reds[1] + reds[2] + reds[3];
  float inv = 1.0f / s;
#pragma unroll
  for (int i = 0; i < 4; i++) {
    bf16x8 o;
#pragma unroll
    for (int j = 0; j < 8; j++) o[j] = (bf16_t)(v[i * 8 + j] * inv);
    *(bf16x8*)(p + t * 32 + i * 8) = o;
  }
}

// --------- row softmax: bf16 logits in, fp32 out + bf16 in-place ----------
__global__ __launch_bounds__(256) void softmax_f_k(bf16_t* __restrict__ fm,
                                                   float* __restrict__ outf) {
  const long row = blockIdx.x;
  bf16_t* p = fm + row * 8192;
  float* q = outf + row * 8192;
  const int t = threadIdx.x;
  float v[32];
#pragma unroll
  for (int i = 0; i < 4; i++) {
    bf16x8 raw = *(const bf16x8*)(p + t * 32 + i * 8);
#pragma unroll
    for (int j = 0; j < 8; j++) v[i * 8 + j] = (float)raw[j];
  }
  float m = -1e30f;
#pragma unroll
  for (int i = 0; i < 32; i++) m = fmaxf(m, v[i]);
  for (int off = 32; off; off >>= 1) m = fmaxf(m, __shfl_xor(m, off, 64));
  __shared__ float redm[4], reds[4];
  if ((t & 63) == 0) redm[t >> 6] = m;
  __syncthreads();
  m = fmaxf(fmaxf(redm[0], redm[1]), fmaxf(redm[2], redm[3]));
  float s = 0.f;
#pragma unroll
  for (int i = 0; i < 32; i++) {
    v[i] = __expf(v[i] - m);
    s += v[i];
  }
  for (int off = 32; off; off >>= 1) s += __shfl_xor(s, off, 64);
  if ((t & 63) == 0) reds[t >> 6] = s;
  __syncthreads();
  s = reds[0] + reds[1] + reds[2] + reds[3];
  float inv = 1.0f / s;
#pragma unroll
  for (int i = 0; i < 8; i++) {
    float4 o;
    o.x = v[i * 4 + 0] * inv;
    o.y = v[i * 4 + 1] * inv;
    o.z = v[i * 4 + 2] * inv;
    o.w = v[i * 4 + 3] * inv;
    *(float4*)(q + t * 32 + i * 4) = o;
  }
#pragma unroll
  for (int i = 0; i < 4; i++) {
    bf16x8 o;
#pragma unroll
    for (int j = 0; j < 8; j++) o[j] = (bf16_t)(v[i * 8 + j] * inv);
    *(bf16x8*)(p + t * 32 + i * 8) = o;
  }
}

// ---------------------------------------------------------------------------
extern "C" void kernel_launch(void* const* d_in, const int* in_sizes, int n_in,
                              void* d_out, int out_size, void* d_ws,
                              size_t ws_size, hipStream_t stream) {
  const int N = 8192, C = 2048, IC = 1024;
  const float* x = (const float*)d_in[0];
  const float* theta_w = (const float*)d_in[1];
  const float* theta_b = (const float*)d_in[2];
  const float* phi_w = (const float*)d_in[3];
  const float* phi_b = (const float*)d_in[4];
  const float* g_w = (const float*)d_in[5];
  const float* g_b = (const float*)d_in[6];
  const float* W_w = (const float*)d_in[7];
  const float* W_b = (const float*)d_in[8];
  const float* mask_w = (const float*)d_in[9];
  const float* mask_b = (const float*)d_in[10];

  float* z_out = (float*)d_out;            // [N,C] fp32
  float* f_out = z_out + (long)N * C;      // [N,N] fp32

  // d_out-hosted scratch (dead before those regions' final writes):
  bf16_t* ML = (bf16_t*)f_out;             // [N,N] bf16 mask logits -> mask
  bf16_t* th16 = (bf16_t*)z_out;           // [N,IC]
  bf16_t* ph16 = th16 + (long)N * IC;      // [N,IC]
  bf16_t* gT16 = ph16 + (long)N * IC;      // [IC,N]

  char* w = (char*)d_ws;
  bf16_t* xb = (bf16_t*)w;      w += (long)N * C * 2;
  bf16_t* mwb = (bf16_t*)w;     w += (long)N * C * 2;
  bf16_t* thwb = (bf16_t*)w;    w += (long)IC * C * 2;
  bf16_t* phwb = (bf16_t*)w;    w += (long)IC * C * 2;
  bf16_t* gwb = (bf16_t*)w;     w += (long)IC * C * 2;
  bf16_t* Wwb = (bf16_t*)w;     w += (long)C * IC * 2;
  bf16_t* fm = (bf16_t*)w;      w += (long)N * N * 2;   // f*mask logits -> P
  bf16_t* y16 = (bf16_t*)w;     w += (long)N * IC * 2;

  cast_f32_bf16_k<<<8192, 256, 0, stream>>>(x, xb, (long)N * C / 8);
  cast_f32_bf16_k<<<8192, 256, 0, stream>>>(mask_w, mwb, (long)N * C / 8);
  cast_f32_bf16_k<<<1024, 256, 0, stream>>>(theta_w, thwb, (long)IC * C / 8);
  cast_f32_bf16_k<<<1024, 256, 0, stream>>>(phi_w, phwb, (long)IC * C / 8);
  cast_f32_bf16_k<<<1024, 256, 0, stream>>>(g_w, gwb, (long)IC * C / 8);
  cast_f32_bf16_k<<<1024, 256, 0, stream>>>(W_w, Wwb, (long)C * IC / 8);

  // projections (128^2 kernel, XCD-grouped)
  gemm_nt<1, false, false, true, 0><<<dim3(IC / 128, N / 128), 256, 0, stream>>>(
      xb, thwb, theta_b, nullptr, nullptr, nullptr, th16, N, IC, C);
  gemm_nt<1, false, false, true, 0><<<dim3(IC / 128, N / 128), 256, 0, stream>>>(
      xb, phwb, phi_b, nullptr, nullptr, nullptr, ph16, N, IC, C);
  gemm_nt<2, false, false, true, 1><<<dim3(N / 128, IC / 128), 256, 0, stream>>>(
      gwb, xb, g_b, nullptr, nullptr, nullptr, gT16, IC, N, C);
  // mask logits (256^2 2-phase kernel), bias per col
  gemm256<1, false><<<dim3(N / 256, N / 256), 512, 0, stream>>>(
      xb, mwb, mask_b, nullptr, ML, N, N, C);
  softmax_bf16_inplace<<<N, 256, 0, stream>>>(ML);
  // f*mask logits (256^2 2-phase kernel)
  gemm256<0, true><<<dim3(N / 256, N / 256), 512, 0, stream>>>(
      th16, ph16, nullptr, ML, fm, N, N, IC);
  softmax_f_k<<<N, 256, 0, stream>>>(fm, f_out);
  // y = P @ g_x (NT via gT16), XCD-grouped on A rows
  gemm_nt<0, false, false, true, 0><<<dim3(IC / 128, N / 128), 256, 0, stream>>>(
      fm, gT16, nullptr, nullptr, nullptr, nullptr, y16, N, IC, N);
  // z = y @ W_w^T + W_b + x
  gemm_nt<1, false, true, false, 0><<<dim3(C / 128, N / 128), 256, 0, stream>>>(
      y16, Wwb, W_b, nullptr, x, z_out, nullptr, N, C, IC);
}

// Round 8
// 1100.242 us; speedup vs baseline: 2.1383x; 1.0588x over previous
//
#include <hip/hip_runtime.h>
#include <hip/hip_bf16.h>

typedef __bf16 bf16_t;
typedef __bf16 bf16x8 __attribute__((ext_vector_type(8)));
typedef float f32x4 __attribute__((ext_vector_type(4)));

#define GLOAD16(gp, lp) __builtin_amdgcn_global_load_lds(                      \
    (const __attribute__((address_space(1))) void*)(gp),                       \
    (__attribute__((address_space(3))) void*)(lp), 16, 0, 0)
#define BARRIER() asm volatile("s_barrier" ::: "memory")
#define VMC(n) asm volatile("s_waitcnt vmcnt(" #n ")" ::: "memory")
#define LGK0()                                                                 \
  do {                                                                         \
    asm volatile("s_waitcnt lgkmcnt(0)" ::: "memory");                         \
    __builtin_amdgcn_sched_barrier(0);                                         \
  } while (0)

// ---------------- cast fp32 -> bf16 (vectorized x8) ----------------
__global__ __launch_bounds__(256) void cast_f32_bf16_k(
    const float* __restrict__ in, bf16_t* __restrict__ out, long n8) {
  long i = (long)blockIdx.x * blockDim.x + threadIdx.x;
  long stride = (long)gridDim.x * blockDim.x;
  for (; i < n8; i += stride) {
    long e = i * 8;
    float4 a = *(const float4*)(in + e);
    float4 b = *(const float4*)(in + e + 4);
    bf16x8 o;
    o[0] = (__bf16)a.x; o[1] = (__bf16)a.y; o[2] = (__bf16)a.z; o[3] = (__bf16)a.w;
    o[4] = (__bf16)b.x; o[5] = (__bf16)b.y; o[6] = (__bf16)b.z; o[7] = (__bf16)b.w;
    *(bf16x8*)(out + e) = o;
  }
}

// ============ 256x256-tile 8-wave GEMM, BK=64, 1 barrier / 1 vmcnt per
// K-tile. 4 quadrant-phases: same-phase lgkm(0), no mid-tile barriers (waves
// drift; DS bursts hide under SIMD-partner MFMA). LDS: 2 x 64KB buffers
// {A 256x128B, B 256x128B}. 16B slot ^= (row&7); staging inverse-swizzles
// the global source (linear LDS dest). Frag regs: aS 32 + bA 16 + bB 16.
template <int BIAS, bool MUL>
__global__ __launch_bounds__(512, 2) void gemm256(
    const bf16_t* __restrict__ A, const bf16_t* __restrict__ B,
    const float* __restrict__ bias, const bf16_t* __restrict__ mulm,
    bf16_t* __restrict__ out, int M, int N, int K) {
  __shared__ __align__(1024) char lds[131072];
  const int tid = threadIdx.x;
  const int gx = N >> 8;
  int bid = blockIdx.y * gx + blockIdx.x;
  const int nwg = gridDim.x * gridDim.y;  // multiple of 8 for our shapes
  const int cpx = nwg >> 3;
  bid = (bid & 7) * cpx + (bid >> 3);     // XCD-aware bijective swizzle
  const long row0 = (long)(bid / gx) * 256;
  const long col0 = (long)(bid % gx) * 256;
  const long Kl = K;

  const int w = tid >> 6, lane = tid & 63;
  const int wm = w >> 2, wn = w & 3;      // 2M x 4N waves
  const int fr = lane & 15, fq = lane >> 4;

  // read-side bases: row stride 128B; slot(kk,fq) ^= fr&7
  const int arow = (wm * 128 + fr) * 128;           // A region byte base
  const int brow = 32768 + (wn * 64 + fr) * 128;    // B region byte base
  const int sw0 = ((fq ^ (fr & 7)) << 4);           // kk=0
  const int sw1 = (((4 | fq) ^ (fr & 7)) << 4);     // kk=1

  // staging: thread covers phys bytes tid*16 and tid*16+8192 of each 16KB
  // half-tile; row r0 = tid>>3 (second load +64 rows); source k-chunk
  // inverse-swizzled: s0 = (tid&7) ^ (r0&7).
  const int r0 = tid >> 3;
  const int s0 = (tid & 7) ^ (r0 & 7);
  const bf16_t* Ap = A + (row0 + r0) * Kl + s0 * 8;
  const bf16_t* Bp = B + (col0 + r0) * Kl + s0 * 8;
  const int dstA = w * 1024;  // + lane*16 implicit in global_load_lds

#define STG_A(h, U)                                                            \
  {                                                                            \
    const bf16_t* s_ = Ap + (long)(h)*128 * Kl + (long)(U)*64;                 \
    char* d_ = lds + (((U)&1) * 65536) + (h)*16384 + dstA;                     \
    GLOAD16(s_, d_);                                                           \
    GLOAD16(s_ + 64 * Kl, d_ + 8192);                                          \
  }
#define STG_B(h, U)                                                            \
  {                                                                            \
    const bf16_t* s_ = Bp + (long)(h)*128 * Kl + (long)(U)*64;                 \
    char* d_ = lds + (((U)&1) * 65536) + 32768 + (h)*16384 + dstA;             \
    GLOAD16(s_, d_);                                                           \
    GLOAD16(s_ + 64 * Kl, d_ + 8192);                                          \
  }
// A-subtile s (4 i-frags x 2 kk = 8 b128) into aS
#define RD_A(buf, s)                                                           \
  {                                                                            \
    _Pragma("unroll") for (int i = 0; i < 4; ++i) {                            \
      aS[i * 2] = *(const bf16x8*)((buf) + arow + ((s)*4 + i) * 2048 + sw0);   \
      aS[i * 2 + 1] =                                                          \
          *(const bf16x8*)((buf) + arow + ((s)*4 + i) * 2048 + sw1);           \
    }                                                                          \
  }
// B-subtile s (2 j-frags x 2 kk = 4 b128) into dst
#define RD_B(dst, buf, s)                                                      \
  {                                                                            \
    _Pragma("unroll") for (int j = 0; j < 2; ++j) {                            \
      dst[j * 2] = *(const bf16x8*)((buf) + brow + ((s)*2 + j) * 2048 + sw0);  \
      dst[j * 2 + 1] =                                                         \
          *(const bf16x8*)((buf) + brow + ((s)*2 + j) * 2048 + sw1);           \
    }                                                                          \
  }
#define QUAD(BV, I0, J0)                                                       \
  {                                                                            \
    __builtin_amdgcn_s_setprio(1);                                             \
    _Pragma("unroll") for (int i = 0; i < 4; ++i)                              \
        _Pragma("unroll") for (int j = 0; j < 2; ++j)                          \
            _Pragma("unroll") for (int kk = 0; kk < 2; ++kk)                   \
                acc[I0 + i][J0 + j] = __builtin_amdgcn_mfma_f32_16x16x32_bf16( \
                    aS[i * 2 + kk], BV[j * 2 + kk], acc[I0 + i][J0 + j], 0, 0, \
                    0);                                                        \
    __builtin_amdgcn_s_setprio(0);                                             \
  }

  f32x4 acc[8][4] = {};
  bf16x8 aS[8], bA[4], bB[4];
  const int NT = K >> 6;  // >= 2

  // prologue: stage tile 0 into buf0
  STG_A(0, 0); STG_A(1, 0); STG_B(0, 0); STG_B(1, 0);

  for (int T = 0; T < NT; ++T) {
    char* buf = lds + (T & 1) * 65536;
    const bool ST = (T < NT - 1);
    // ph0: tile-T buffer ready (all waves) -> read A0,B0; stage A0(T+1)
    VMC(0);
    BARRIER();
    if (ST) STG_A(0, T + 1);
    RD_A(buf, 0);
    RD_B(bA, buf, 0);
    LGK0();
    QUAD(bA, 0, 0);
    // ph1: read B1; stage A1(T+1)
    RD_B(bB, buf, 1);
    if (ST) STG_A(1, T + 1);
    LGK0();
    QUAD(bB, 0, 2);
    // ph2: read A1; stage B0(T+1)
    RD_A(buf, 1);
    if (ST) STG_B(0, T + 1);
    LGK0();
    QUAD(bB, 4, 2);
    // ph3: stage B1(T+1); B0 frags still live
    if (ST) STG_B(1, T + 1);
    QUAD(bA, 4, 0);
  }
#undef STG_A
#undef STG_B
#undef RD_A
#undef RD_B
#undef QUAD

  // epilogue: C/D layout col=lane&15, row=(lane>>4)*4+r
#pragma unroll
  for (int i = 0; i < 8; ++i)
#pragma unroll
    for (int j = 0; j < 4; ++j)
#pragma unroll
      for (int r = 0; r < 4; ++r) {
        long gi = row0 + wm * 128 + i * 16 + fq * 4 + r;
        long gj = col0 + wn * 64 + j * 16 + fr;
        float v = acc[i][j][r];
        if (BIAS == 1) v += bias[gj];
        long idx = gi * (long)N + gj;
        if (MUL) v *= (float)mulm[idx];
        out[idx] = (bf16_t)v;
      }
}

// ---------------- NT GEMM (m97 128x128), slot-swizzled, XCD-grouped --------
// GROUP 0: blocks sharing an A row-tile grouped on one XCD (requires gy%8==0)
// GROUP 1: blocks sharing a B col-tile grouped on one XCD (requires gx%8==0)
template <int BIAS, bool MUL, bool RES, bool OUTBF16, int GROUP>
__global__ __launch_bounds__(256) void gemm_nt(
    const bf16_t* __restrict__ A, const bf16_t* __restrict__ B,
    const float* __restrict__ bias, const bf16_t* __restrict__ mulm,
    const float* __restrict__ res, float* __restrict__ outf,
    bf16_t* __restrict__ outb, int M, int N, int K) {
  __shared__ bf16_t As[128 * 32];
  __shared__ bf16_t Bs[128 * 32];
  const int tid = threadIdx.x;
  const int gx = gridDim.x, gy = gridDim.y;
  const int n = blockIdx.y * gx + blockIdx.x;
  const int xcd = n & 7, q = n >> 3;
  int br, bc;
  if (GROUP == 0) { br = xcd + 8 * (q / gx); bc = q % gx; }
  else            { bc = xcd + 8 * (q / gy); br = q % gy; }
  const long row0 = (long)br * 128;
  const long col0 = (long)bc * 128;
  const int wid = tid >> 6, lane = tid & 63;
  const int wr = (wid >> 1) * 64;
  const int wc = (wid & 1) * 64;
  const int fr = lane & 15, fq = lane >> 4;
  const int sx = (fr >> 1) & 3;
  const int srow = tid >> 2;
  const int scol = ((tid & 3) ^ ((srow >> 1) & 3)) * 8;  // inverse-swz source

  f32x4 acc[4][4] = {};

  const bf16_t* Ag = A + (row0 + srow) * (long)K + scol;
  const bf16_t* Bg = B + (col0 + srow) * (long)K + scol;
  const long k64 = 64L * K;
  bf16_t* ldsA = As + wid * 512;
  bf16_t* ldsB = Bs + wid * 512;

  for (int k0 = 0; k0 < K; k0 += 32) {
    GLOAD16(Ag + k0, ldsA);
    GLOAD16(Ag + k0 + k64, ldsA + 2048);
    GLOAD16(Bg + k0, ldsB);
    GLOAD16(Bg + k0 + k64, ldsB + 2048);
    __syncthreads();
    bf16x8 av[4], bv[4];
#pragma unroll
    for (int i = 0; i < 4; i++)
      av[i] = *(const bf16x8*)(As + (wr + i * 16 + fr) * 32 + ((fq ^ sx) << 3));
#pragma unroll
    for (int j = 0; j < 4; j++)
      bv[j] = *(const bf16x8*)(Bs + (wc + j * 16 + fr) * 32 + ((fq ^ sx) << 3));
#pragma unroll
    for (int i = 0; i < 4; i++)
#pragma unroll
      for (int j = 0; j < 4; j++)
        acc[i][j] = __builtin_amdgcn_mfma_f32_16x16x32_bf16(av[i], bv[j],
                                                            acc[i][j], 0, 0, 0);
    __syncthreads();
  }

#pragma unroll
  for (int i = 0; i < 4; i++) {
#pragma unroll
    for (int j = 0; j < 4; j++) {
#pragma unroll
      for (int r = 0; r < 4; r++) {
        long gi = row0 + wr + i * 16 + fq * 4 + r;
        long gj = col0 + wc + j * 16 + fr;
        float v = acc[i][j][r];
        if (BIAS == 1) v += bias[gj];
        if (BIAS == 2) v += bias[gi];
        long idx = gi * (long)N + gj;
        if (MUL) v *= (float)mulm[idx];
        if (RES) v += res[idx];
        if (OUTBF16) outb[idx] = (bf16_t)v;
        else outf[idx] = v;
      }
    }
  }
}

// ---------------- row softmax over 8192 cols, bf16 in-place ----------------
__global__ __launch_bounds__(256) void softmax_bf16_inplace(
    bf16_t* __restrict__ buf) {
  const long row = blockIdx.x;
  bf16_t* p = buf + row * 8192;
  const int t = threadIdx.x;
  float v[32];
#pragma unroll
  for (int i = 0; i < 4; i++) {
    bf16x8 raw = *(const bf16x8*)(p + t * 32 + i * 8);
#pragma unroll
    for (int j = 0; j < 8; j++) v[i * 8 + j] = (float)raw[j];
  }
  float m = -1e30f;
#pragma unroll
  for (int i = 0; i < 32; i++) m = fmaxf(m, v[i]);
  for (int off = 32; off; off >>= 1) m = fmaxf(m, __shfl_xor(m, off, 64));
  __shared__ float redm[4], reds[4];
  if ((t & 63) == 0) redm[t >> 6] = m;
  __syncthreads();
  m = fmaxf(fmaxf(redm[0], redm[1]), fmaxf(redm[2], redm[3]));
  float s = 0.f;
#pragma unroll
  for (int i = 0; i < 32; i++) {
    v[i] = __expf(v[i] - m);
    s += v[i];
  }
  for (int off = 32; off; off >>= 1) s += __shfl_xor(s, off, 64);
  if ((t & 63) == 0) reds[t >> 6] = s;
  __syncthreads();
  s = reds[0] + reds[1] + reds[2] + reds[3];
  float inv = 1.0f / s;
#pragma unroll
  for (int i = 0; i < 4; i++) {
    bf16x8 o;
#pragma unroll
    for (int j = 0; j < 8; j++) o[j] = (bf16_t)(v[i * 8 + j] * inv);
    *(bf16x8*)(p + t * 32 + i * 8) = o;
  }
}

// --------- row softmax: bf16 logits in, fp32 out + bf16 in-place ----------
__global__ __launch_bounds__(256) void softmax_f_k(bf16_t* __restrict__ fm,
                                                   float* __restrict__ outf) {
  const long row = blockIdx.x;
  bf16_t* p = fm + row * 8192;
  float* q = outf + row * 8192;
  const int t = threadIdx.x;
  float v[32];
#pragma unroll
  for (int i = 0; i < 4; i++) {
    bf16x8 raw = *(const bf16x8*)(p + t * 32 + i * 8);
#pragma unroll
    for (int j = 0; j < 8; j++) v[i * 8 + j] = (float)raw[j];
  }
  float m = -1e30f;
#pragma unroll
  for (int i = 0; i < 32; i++) m = fmaxf(m, v[i]);
  for (int off = 32; off; off >>= 1) m = fmaxf(m, __shfl_xor(m, off, 64));
  __shared__ float redm[4], reds[4];
  if ((t & 63) == 0) redm[t >> 6] = m;
  __syncthreads();
  m = fmaxf(fmaxf(redm[0], redm[1]), fmaxf(redm[2], redm[3]));
  float s = 0.f;
#pragma unroll
  for (int i = 0; i < 32; i++) {
    v[i] = __expf(v[i] - m);
    s += v[i];
  }
  for (int off = 32; off; off >>= 1) s += __shfl_xor(s, off, 64);
  if ((t & 63) == 0) reds[t >> 6] = s;
  __syncthreads();
  s = reds[0] + reds[1] + reds[2] + reds[3];
  float inv = 1.0f / s;
#pragma unroll
  for (int i = 0; i < 8; i++) {
    float4 o;
    o.x = v[i * 4 + 0] * inv;
    o.y = v[i * 4 + 1] * inv;
    o.z = v[i * 4 + 2] * inv;
    o.w = v[i * 4 + 3] * inv;
    *(float4*)(q + t * 32 + i * 4) = o;
  }
#pragma unroll
  for (int i = 0; i < 4; i++) {
    bf16x8 o;
#pragma unroll
    for (int j = 0; j < 8; j++) o[j] = (bf16_t)(v[i * 8 + j] * inv);
    *(bf16x8*)(p + t * 32 + i * 8) = o;
  }
}

// ---------------------------------------------------------------------------
extern "C" void kernel_launch(void* const* d_in, const int* in_sizes, int n_in,
                              void* d_out, int out_size, void* d_ws,
                              size_t ws_size, hipStream_t stream) {
  const int N = 8192, C = 2048, IC = 1024;
  const float* x = (const float*)d_in[0];
  const float* theta_w = (const float*)d_in[1];
  const float* theta_b = (const float*)d_in[2];
  const float* phi_w = (const float*)d_in[3];
  const float* phi_b = (const float*)d_in[4];
  const float* g_w = (const float*)d_in[5];
  const float* g_b = (const float*)d_in[6];
  const float* W_w = (const float*)d_in[7];
  const float* W_b = (const float*)d_in[8];
  const float* mask_w = (const float*)d_in[9];
  const float* mask_b = (const float*)d_in[10];

  float* z_out = (float*)d_out;            // [N,C] fp32
  float* f_out = z_out + (long)N * C;      // [N,N] fp32

  // d_out-hosted scratch (dead before those regions' final writes):
  bf16_t* ML = (bf16_t*)f_out;             // [N,N] bf16 mask logits -> mask
  bf16_t* th16 = (bf16_t*)z_out;           // [N,IC]
  bf16_t* ph16 = th16 + (long)N * IC;      // [N,IC]
  bf16_t* gT16 = ph16 + (long)N * IC;      // [IC,N]

  char* w = (char*)d_ws;
  bf16_t* xb = (bf16_t*)w;      w += (long)N * C * 2;
  bf16_t* mwb = (bf16_t*)w;     w += (long)N * C * 2;
  bf16_t* thwb = (bf16_t*)w;    w += (long)IC * C * 2;
  bf16_t* phwb = (bf16_t*)w;    w += (long)IC * C * 2;
  bf16_t* gwb = (bf16_t*)w;     w += (long)IC * C * 2;
  bf16_t* Wwb = (bf16_t*)w;     w += (long)C * IC * 2;
  bf16_t* fm = (bf16_t*)w;      w += (long)N * N * 2;   // f*mask logits -> P
  bf16_t* y16 = (bf16_t*)w;     w += (long)N * IC * 2;

  cast_f32_bf16_k<<<8192, 256, 0, stream>>>(x, xb, (long)N * C / 8);
  cast_f32_bf16_k<<<8192, 256, 0, stream>>>(mask_w, mwb, (long)N * C / 8);
  cast_f32_bf16_k<<<1024, 256, 0, stream>>>(theta_w, thwb, (long)IC * C / 8);
  cast_f32_bf16_k<<<1024, 256, 0, stream>>>(phi_w, phwb, (long)IC * C / 8);
  cast_f32_bf16_k<<<1024, 256, 0, stream>>>(g_w, gwb, (long)IC * C / 8);
  cast_f32_bf16_k<<<1024, 256, 0, stream>>>(W_w, Wwb, (long)C * IC / 8);

  // projections (128^2 kernel, XCD-grouped)
  gemm_nt<1, false, false, true, 0><<<dim3(IC / 128, N / 128), 256, 0, stream>>>(
      xb, thwb, theta_b, nullptr, nullptr, nullptr, th16, N, IC, C);
  gemm_nt<1, false, false, true, 0><<<dim3(IC / 128, N / 128), 256, 0, stream>>>(
      xb, phwb, phi_b, nullptr, nullptr, nullptr, ph16, N, IC, C);
  gemm_nt<2, false, false, true, 1><<<dim3(N / 128, IC / 128), 256, 0, stream>>>(
      gwb, xb, g_b, nullptr, nullptr, nullptr, gT16, IC, N, C);
  // mask logits (256^2 4-phase/1-barrier kernel), bias per col
  gemm256<1, false><<<dim3(N / 256, N / 256), 512, 0, stream>>>(
      xb, mwb, mask_b, nullptr, ML, N, N, C);
  softmax_bf16_inplace<<<N, 256, 0, stream>>>(ML);
  // f*mask logits
  gemm256<0, true><<<dim3(N / 256, N / 256), 512, 0, stream>>>(
      th16, ph16, nullptr, ML, fm, N, N, IC);
  softmax_f_k<<<N, 256, 0, stream>>>(fm, f_out);
  // y = P @ g_x (NT via gT16), XCD-grouped on A rows
  gemm_nt<0, false, false, true, 0><<<dim3(IC / 128, N / 128), 256, 0, stream>>>(
      fm, gT16, nullptr, nullptr, nullptr, nullptr, y16, N, IC, N);
  // z = y @ W_w^T + W_b + x
  gemm_nt<1, false, true, false, 0><<<dim3(C / 128, N / 128), 256, 0, stream>>>(
      y16, Wwb, W_b, nullptr, x, z_out, nullptr, N, C, IC);
}